// Round 1
// baseline (1060.372 us; speedup 1.0000x reference)
//
#include <hip/hip_runtime.h>
#include <hip/hip_bf16.h>

typedef __attribute__((ext_vector_type(8))) short short8;
typedef __attribute__((ext_vector_type(4))) float f32x4;

#define NNODES 8192
#define FDIM 128

// ---------------- degree + norm ----------------
__global__ void k_deg(const int* __restrict__ src, const int* __restrict__ dst,
                      float* __restrict__ deg_s, float* __restrict__ deg_d, int E) {
    int e = blockIdx.x * blockDim.x + threadIdx.x;
    if (e < E) {
        atomicAdd(&deg_s[src[e]], 1.0f);
        atomicAdd(&deg_d[dst[e]], 1.0f);
    }
}

__global__ void k_rsqrt(float* __restrict__ d, int n) {
    int i = blockIdx.x * blockDim.x + threadIdx.x;
    if (i < n) d[i] = rsqrtf(fmaxf(d[i], 1.0f));
}

// ---------------- small linear: Y[row] = (X[row] @ W) * norm[row] ----------------
// block = 128 threads (one output col each), R rows per block.
template<int K, int R>
__global__ void k_linear_norm(const float* __restrict__ X, const float* __restrict__ W,
                              const float* __restrict__ norm, float* __restrict__ Y) {
    int col = threadIdx.x;
    int row0 = blockIdx.x * R;
    float acc[R];
#pragma unroll
    for (int r = 0; r < R; ++r) acc[r] = 0.f;
    for (int k = 0; k < K; ++k) {
        float w = W[k * FDIM + col];
#pragma unroll
        for (int r = 0; r < R; ++r)
            acc[r] = fmaf(X[(size_t)(row0 + r) * K + k], w, acc[r]);
    }
#pragma unroll
    for (int r = 0; r < R; ++r)
        Y[(size_t)(row0 + r) * FDIM + col] = acc[r] * norm[row0 + r];
}

// ---------------- edge scatter: AGG[dst[e]] += Y[src[e]]  (128 f32/edge) ----------------
// 32 threads per edge, float4 per thread.
__global__ void k_scatter(const float* __restrict__ Y, const int* __restrict__ src,
                          const int* __restrict__ dst, float* __restrict__ AGG, int E) {
    int t = blockIdx.x * blockDim.x + threadIdx.x;
    int e = t >> 5;
    if (e >= E) return;
    int c = (t & 31) << 2;
    int s = src[e], d = dst[e];
    float4 v = *(const float4*)(Y + (size_t)s * FDIM + c);
    float* out = AGG + (size_t)d * FDIM + c;
    atomicAdd(out + 0, v.x);
    atomicAdd(out + 1, v.y);
    atomicAdd(out + 2, v.z);
    atomicAdd(out + 3, v.w);
}

// ---------------- finalize: H = act(AGG * norm_dst + bias) ----------------
__global__ void k_finalize_relu(const float* __restrict__ AGG, const float* __restrict__ nd,
                                const float* __restrict__ bias, float* __restrict__ H, int total) {
    int i = blockIdx.x * blockDim.x + threadIdx.x;
    if (i >= total) return;
    int row = i >> 7, col = i & (FDIM - 1);
    float v = AGG[i] * nd[row] + bias[col];
    H[i] = fmaxf(v, 0.f);
}

__global__ void k_finalize_bf16(const float* __restrict__ AGG, const float* __restrict__ nd,
                                const float* __restrict__ bias, __hip_bfloat16* __restrict__ H,
                                int total) {
    int i = blockIdx.x * blockDim.x + threadIdx.x;
    if (i >= total) return;
    int row = i >> 7, col = i & (FDIM - 1);
    float v = AGG[i] * nd[row] + bias[col];
    H[i] = __float2bfloat16(v);
}

// ---------------- decode: C = sigmoid(H @ H^T), H is [8192][128] bf16 ----------------
// 128x128 tile per block, 4 waves, mfma_f32_16x16x32_bf16, XOR-swizzled LDS.
__global__ __launch_bounds__(256) void k_decode(const __hip_bfloat16* __restrict__ H,
                                                float* __restrict__ C) {
    __shared__ __align__(16) unsigned char smem[65536];
    unsigned char* sA = smem;
    unsigned char* sB = smem + 32768;
    const int ti = blockIdx.x, tj = blockIdx.y;
    const int t = threadIdx.x;
    const unsigned char* gH = (const unsigned char*)H;

    // stage A (rows ti*128..+128) and B (rows tj*128..+128); each row = 256 bytes.
    // 2048 16B-chunks per tile, 8 per thread. Swizzle bits [6:4] ^= (row&7)<<4.
#pragma unroll
    for (int i = 0; i < 8; ++i) {
        int chunk = t + i * 256;
        int row = chunk >> 4;
        int cc = (chunk & 15) << 4;
        int lofs = row * 256 + (cc ^ ((row & 7) << 4));
        *(float4*)(sA + lofs) = *(const float4*)(gH + ((size_t)(ti * 128 + row) << 8) + cc);
        *(float4*)(sB + lofs) = *(const float4*)(gH + ((size_t)(tj * 128 + row) << 8) + cc);
    }
    __syncthreads();

    const int w = t >> 6, lane = t & 63;
    const int wr = (w >> 1) * 64, wc = (w & 1) * 64;
    const int lr = lane & 15;
    const int lk = (lane >> 4) * 16;  // byte offset of this lane's 8-element k-chunk

    f32x4 acc[4][4] = {};

#pragma unroll
    for (int ks = 0; ks < 4; ++ks) {
        short8 af[4], bfr[4];
#pragma unroll
        for (int mi = 0; mi < 4; ++mi) {
            int row = wr + mi * 16 + lr;
            int off = row * 256 + ((ks * 64 + lk) ^ ((row & 7) << 4));
            af[mi] = *(const short8*)(sA + off);
        }
#pragma unroll
        for (int ni = 0; ni < 4; ++ni) {
            int row = wc + ni * 16 + lr;
            int off = row * 256 + ((ks * 64 + lk) ^ ((row & 7) << 4));
            bfr[ni] = *(const short8*)(sB + off);
        }
#pragma unroll
        for (int mi = 0; mi < 4; ++mi)
#pragma unroll
            for (int ni = 0; ni < 4; ++ni)
                acc[mi][ni] = __builtin_amdgcn_mfma_f32_16x16x32_bf16(af[mi], bfr[ni],
                                                                      acc[mi][ni], 0, 0, 0);
    }

    // epilogue: C/D layout col=lane&15, row=(lane>>4)*4+reg (guide m89)
    const int rbase = (lane >> 4) * 4;
    const int cbase = lane & 15;
#pragma unroll
    for (int mi = 0; mi < 4; ++mi) {
#pragma unroll
        for (int ni = 0; ni < 4; ++ni) {
#pragma unroll
            for (int r = 0; r < 4; ++r) {
                int row = ti * 128 + wr + mi * 16 + rbase + r;
                int col = tj * 128 + wc + ni * 16 + cbase;
                float v = acc[mi][ni][r];
                C[(size_t)row * NNODES + col] = 1.0f / (1.0f + __expf(-v));
            }
        }
    }
}

extern "C" void kernel_launch(void* const* d_in, const int* in_sizes, int n_in,
                              void* d_out, int out_size, void* d_ws, size_t ws_size,
                              hipStream_t stream) {
    const float* x  = (const float*)d_in[0];
    const int* src  = (const int*)d_in[1];
    const int* dst  = (const int*)d_in[2];
    const float* W1 = (const float*)d_in[3];
    const float* b1 = (const float*)d_in[4];
    const float* W2 = (const float*)d_in[5];
    const float* b2 = (const float*)d_in[6];
    float* out = (float*)d_out;
    const int E = in_sizes[1];

    char* ws = (char*)d_ws;
    float* norm_s = (float*)ws;                         // 8192 f32
    float* norm_d = (float*)(ws + 32768);               // 8192 f32
    float* bufA   = (float*)(ws + 65536);               // 8192*128 f32 = 4MB
    float* bufB   = (float*)(ws + 65536 + 4194304);     // 4MB
    __hip_bfloat16* h2bf = (__hip_bfloat16*)(ws + 65536 + 8388608);  // 2MB

    const int total = NNODES * FDIM;

    // degrees -> norms
    hipMemsetAsync(norm_s, 0, 65536, stream);  // zeroes both norm_s and norm_d
    k_deg<<<(E + 255) / 256, 256, 0, stream>>>(src, dst, norm_s, norm_d, E);
    k_rsqrt<<<(2 * NNODES + 255) / 256, 256, 0, stream>>>(norm_s, 2 * NNODES);

    // layer 1: y = (x@W1)*ns -> scatter -> h1 = relu(agg*nd + b1)
    k_linear_norm<256, 16><<<NNODES / 16, 128, 0, stream>>>(x, W1, norm_s, bufA);
    hipMemsetAsync(bufB, 0, (size_t)total * 4, stream);
    k_scatter<<<(E * 32 + 255) / 256, 256, 0, stream>>>(bufA, src, dst, bufB, E);
    k_finalize_relu<<<(total + 255) / 256, 256, 0, stream>>>(bufB, norm_d, b1, bufA, total);

    // layer 2: y2 = (h1@W2)*ns -> scatter -> h2 = agg*nd + b2 (bf16)
    k_linear_norm<128, 16><<<NNODES / 16, 128, 0, stream>>>(bufA, W2, norm_s, bufB);
    hipMemsetAsync(bufA, 0, (size_t)total * 4, stream);
    k_scatter<<<(E * 32 + 255) / 256, 256, 0, stream>>>(bufB, src, dst, bufA, E);
    k_finalize_bf16<<<(total + 255) / 256, 256, 0, stream>>>(bufA, norm_d, b2, h2bf, total);

    // decode: out = sigmoid(h2 @ h2^T)
    k_decode<<<dim3(64, 64), 256, 0, stream>>>(h2bf, out);
}

// Round 2
// 209.880 us; speedup vs baseline: 5.0523x; 5.0523x over previous
//
#include <hip/hip_runtime.h>
#include <hip/hip_bf16.h>

typedef __attribute__((ext_vector_type(8))) short short8;
typedef __attribute__((ext_vector_type(4))) float f32x4;

#define NNODES 8192
#define FDIM 128

// ---------------- int degree count ----------------
__global__ void k_deg_int(const int* __restrict__ src, const int* __restrict__ dst,
                          int* __restrict__ cnt_s, int* __restrict__ cnt_d, int E) {
    int e = blockIdx.x * blockDim.x + threadIdx.x;
    if (e < E) {
        atomicAdd(&cnt_s[src[e]], 1);
        atomicAdd(&cnt_d[dst[e]], 1);
    }
}

__global__ void k_norms(const int* __restrict__ cnt_s, const int* __restrict__ cnt_d,
                        float* __restrict__ norm_s, float* __restrict__ norm_d, int n) {
    int i = blockIdx.x * blockDim.x + threadIdx.x;
    if (i < n) {
        norm_s[i] = rsqrtf(fmaxf((float)cnt_s[i], 1.0f));
        norm_d[i] = rsqrtf(fmaxf((float)cnt_d[i], 1.0f));
    }
}

// ---------------- single-block exclusive scan over 8192 ints ----------------
__global__ __launch_bounds__(256) void k_scan(const int* __restrict__ cnt,
                                              int* __restrict__ row_start,
                                              int* __restrict__ cursor, int n) {
    __shared__ int partial[256];
    __shared__ int offs[257];
    int t = threadIdx.x;
    int base = t * 32;
    int local[32];
    int s = 0;
#pragma unroll
    for (int i = 0; i < 32; ++i) { local[i] = s; s += cnt[base + i]; }
    partial[t] = s;
    __syncthreads();
    if (t == 0) {
        int acc = 0;
        for (int i = 0; i < 256; ++i) { offs[i] = acc; acc += partial[i]; }
        offs[256] = acc;
    }
    __syncthreads();
    int o = offs[t];
#pragma unroll
    for (int i = 0; i < 32; ++i) {
        int v = o + local[i];
        row_start[base + i] = v;
        cursor[base + i] = v;
    }
    if (t == 0) row_start[n] = offs[256];
}

__global__ void k_fill(const int* __restrict__ src, const int* __restrict__ dst,
                       int* __restrict__ cursor, int* __restrict__ csr_src, int E) {
    int e = blockIdx.x * blockDim.x + threadIdx.x;
    if (e < E) {
        int pos = atomicAdd(&cursor[dst[e]], 1);
        csr_src[pos] = src[e];
    }
}

// ---------------- small linear: Y[row] = (X[row] @ W) * norm[row] ----------------
template<int K, int R>
__global__ void k_linear_norm(const float* __restrict__ X, const float* __restrict__ W,
                              const float* __restrict__ norm, float* __restrict__ Y) {
    int col = threadIdx.x;
    int row0 = blockIdx.x * R;
    float acc[R];
#pragma unroll
    for (int r = 0; r < R; ++r) acc[r] = 0.f;
    for (int k = 0; k < K; ++k) {
        float w = W[k * FDIM + col];
#pragma unroll
        for (int r = 0; r < R; ++r)
            acc[r] = fmaf(X[(size_t)(row0 + r) * K + k], w, acc[r]);
    }
#pragma unroll
    for (int r = 0; r < R; ++r)
        Y[(size_t)(row0 + r) * FDIM + col] = acc[r] * norm[row0 + r];
}

// ---------------- gather-aggregate + finalize ----------------
// 32 lanes per node (float4 per lane), 8 nodes per 256-thread block.
// out = act( (sum_{e in row} Y[csr_src[e]]) * nd[node] + bias )
static __device__ inline unsigned short f2bf(float f) {
    union { float f; unsigned int u; } a; a.f = f;
    unsigned int u = a.u;
    unsigned int r = u + 0x7FFFu + ((u >> 16) & 1u);
    return (unsigned short)(r >> 16);
}

template<int MODE>  // 0: relu -> f32 out; 1: identity -> bf16 out
__global__ __launch_bounds__(256) void k_gather_agg(const float* __restrict__ Y,
                                                    const int* __restrict__ row_start,
                                                    const int* __restrict__ csr_src,
                                                    const float* __restrict__ nd,
                                                    const float* __restrict__ bias,
                                                    void* __restrict__ outp) {
    int t = threadIdx.x;
    int node = blockIdx.x * 8 + (t >> 5);
    int c4 = (t & 31) << 2;  // column base (0..124 step 4)
    int beg = row_start[node], end = row_start[node + 1];
    f32x4 acc = {0.f, 0.f, 0.f, 0.f};
    int e = beg;
    for (; e + 1 < end; e += 2) {
        int s0 = csr_src[e], s1 = csr_src[e + 1];
        f32x4 v0 = *(const f32x4*)(Y + ((size_t)s0 << 7) + c4);
        f32x4 v1 = *(const f32x4*)(Y + ((size_t)s1 << 7) + c4);
        acc += v0;
        acc += v1;
    }
    if (e < end) {
        int s0 = csr_src[e];
        acc += *(const f32x4*)(Y + ((size_t)s0 << 7) + c4);
    }
    float scale = nd[node];
    f32x4 b = *(const f32x4*)(bias + c4);
    f32x4 v = acc * scale + b;
    if (MODE == 0) {
#pragma unroll
        for (int i = 0; i < 4; ++i) v[i] = fmaxf(v[i], 0.f);
        *(f32x4*)((float*)outp + ((size_t)node << 7) + c4) = v;
    } else {
        ushort4 u;
        u.x = f2bf(v[0]); u.y = f2bf(v[1]); u.z = f2bf(v[2]); u.w = f2bf(v[3]);
        *(ushort4*)((unsigned short*)outp + ((size_t)node << 7) + c4) = u;
    }
}

// ---------------- decode: C = sigmoid(H @ H^T), H is [8192][128] bf16 ----------------
// 128x128 tile per block, 4 waves, mfma_f32_16x16x32_bf16, XOR-swizzled LDS.
__global__ __launch_bounds__(256) void k_decode(const __hip_bfloat16* __restrict__ H,
                                                float* __restrict__ C) {
    __shared__ __align__(16) unsigned char smem[65536];
    unsigned char* sA = smem;
    unsigned char* sB = smem + 32768;
    const int ti = blockIdx.x, tj = blockIdx.y;
    const int t = threadIdx.x;
    const unsigned char* gH = (const unsigned char*)H;

#pragma unroll
    for (int i = 0; i < 8; ++i) {
        int chunk = t + i * 256;
        int row = chunk >> 4;
        int cc = (chunk & 15) << 4;
        int lofs = row * 256 + (cc ^ ((row & 7) << 4));
        *(float4*)(sA + lofs) = *(const float4*)(gH + ((size_t)(ti * 128 + row) << 8) + cc);
        *(float4*)(sB + lofs) = *(const float4*)(gH + ((size_t)(tj * 128 + row) << 8) + cc);
    }
    __syncthreads();

    const int w = t >> 6, lane = t & 63;
    const int wr = (w >> 1) * 64, wc = (w & 1) * 64;
    const int lr = lane & 15;
    const int lk = (lane >> 4) * 16;

    f32x4 acc[4][4] = {};

#pragma unroll
    for (int ks = 0; ks < 4; ++ks) {
        short8 af[4], bfr[4];
#pragma unroll
        for (int mi = 0; mi < 4; ++mi) {
            int row = wr + mi * 16 + lr;
            int off = row * 256 + ((ks * 64 + lk) ^ ((row & 7) << 4));
            af[mi] = *(const short8*)(sA + off);
        }
#pragma unroll
        for (int ni = 0; ni < 4; ++ni) {
            int row = wc + ni * 16 + lr;
            int off = row * 256 + ((ks * 64 + lk) ^ ((row & 7) << 4));
            bfr[ni] = *(const short8*)(sB + off);
        }
#pragma unroll
        for (int mi = 0; mi < 4; ++mi)
#pragma unroll
            for (int ni = 0; ni < 4; ++ni)
                acc[mi][ni] = __builtin_amdgcn_mfma_f32_16x16x32_bf16(af[mi], bfr[ni],
                                                                      acc[mi][ni], 0, 0, 0);
    }

    const int rbase = (lane >> 4) * 4;
    const int cbase = lane & 15;
#pragma unroll
    for (int mi = 0; mi < 4; ++mi) {
#pragma unroll
        for (int ni = 0; ni < 4; ++ni) {
#pragma unroll
            for (int r = 0; r < 4; ++r) {
                int row = ti * 128 + wr + mi * 16 + rbase + r;
                int col = tj * 128 + wc + ni * 16 + cbase;
                float v = acc[mi][ni][r];
                C[(size_t)row * NNODES + col] = 1.0f / (1.0f + __expf(-v));
            }
        }
    }
}

extern "C" void kernel_launch(void* const* d_in, const int* in_sizes, int n_in,
                              void* d_out, int out_size, void* d_ws, size_t ws_size,
                              hipStream_t stream) {
    const float* x  = (const float*)d_in[0];
    const int* src  = (const int*)d_in[1];
    const int* dst  = (const int*)d_in[2];
    const float* W1 = (const float*)d_in[3];
    const float* b1 = (const float*)d_in[4];
    const float* W2 = (const float*)d_in[5];
    const float* b2 = (const float*)d_in[6];
    float* out = (float*)d_out;
    const int E = in_sizes[1];

    char* ws = (char*)d_ws;
    float* norm_s    = (float*)(ws + 0);
    float* norm_d    = (float*)(ws + (32 << 10));
    int*   cnt_s     = (int*)(ws + (64 << 10));
    int*   cnt_d     = (int*)(ws + (96 << 10));
    int*   row_start = (int*)(ws + (128 << 10));   // 8193 ints
    int*   cursor    = (int*)(ws + (164 << 10));
    int*   csr_src   = (int*)(ws + (196 << 10));   // E ints = 1MB
    char*  big       = ws + (196 << 10) + ((size_t)E * 4);
    float* bufA      = (float*)big;                 // 4MB
    float* bufB      = (float*)(big + (4 << 20));   // 4MB
    __hip_bfloat16* h2bf = (__hip_bfloat16*)(big + (8 << 20));  // 2MB

    // zero the degree counters (harness does not re-zero ws between replays)
    hipMemsetAsync(cnt_s, 0, 64 << 10, stream);  // covers cnt_s + cnt_d

    // degrees, norms, CSR (graph shared by both layers)
    k_deg_int<<<(E + 255) / 256, 256, 0, stream>>>(src, dst, cnt_s, cnt_d, E);
    k_norms<<<(NNODES + 255) / 256, 256, 0, stream>>>(cnt_s, cnt_d, norm_s, norm_d, NNODES);
    k_scan<<<1, 256, 0, stream>>>(cnt_d, row_start, cursor, NNODES);
    k_fill<<<(E + 255) / 256, 256, 0, stream>>>(src, dst, cursor, csr_src, E);

    // layer 1: y1 = (x@W1)*ns ; h1 = relu(gather(y1)*nd + b1)
    k_linear_norm<256, 16><<<NNODES / 16, 128, 0, stream>>>(x, W1, norm_s, bufA);
    k_gather_agg<0><<<NNODES / 8, 256, 0, stream>>>(bufA, row_start, csr_src, norm_d, b1, bufB);

    // layer 2: y2 = (h1@W2)*ns ; h2 = gather(y2)*nd + b2 -> bf16
    k_linear_norm<128, 16><<<NNODES / 16, 128, 0, stream>>>(bufB, W2, norm_s, bufA);
    k_gather_agg<1><<<NNODES / 8, 256, 0, stream>>>(bufA, row_start, csr_src, norm_d, b2, h2bf);

    // decode: out = sigmoid(h2 @ h2^T)
    k_decode<<<dim3(64, 64), 256, 0, stream>>>(h2bf, out);
}

// Round 3
// 189.897 us; speedup vs baseline: 5.5839x; 1.1052x over previous
//
#include <hip/hip_runtime.h>
#include <hip/hip_bf16.h>

typedef __attribute__((ext_vector_type(8))) short short8;
typedef __attribute__((ext_vector_type(4))) float f32x4;

#define NNODES 8192
#define FDIM 128

// ---------------- zero ints (replaces hipMemsetAsync) ----------------
__global__ void k_zero(int* __restrict__ p, int n) {
    int i = blockIdx.x * blockDim.x + threadIdx.x;
    if (i < n) p[i] = 0;
}

// ---------------- int degree count ----------------
__global__ void k_deg_int(const int* __restrict__ src, const int* __restrict__ dst,
                          int* __restrict__ cnt_s, int* __restrict__ cnt_d, int E) {
    int e = blockIdx.x * blockDim.x + threadIdx.x;
    if (e < E) {
        atomicAdd(&cnt_s[src[e]], 1);
        atomicAdd(&cnt_d[dst[e]], 1);
    }
}

// ---------------- single-block: norms + exclusive scan over cnt_d ----------------
__global__ __launch_bounds__(256) void k_scan_norms(const int* __restrict__ cnt_s,
                                                    const int* __restrict__ cnt_d,
                                                    float* __restrict__ norm_s,
                                                    float* __restrict__ norm_d,
                                                    int* __restrict__ row_start,
                                                    int* __restrict__ cursor, int n) {
    __shared__ int partial[256];
    __shared__ int offs[257];
    int t = threadIdx.x;
    int base = t * 32;
    // norms
#pragma unroll
    for (int i = 0; i < 32; ++i) {
        norm_s[base + i] = rsqrtf(fmaxf((float)cnt_s[base + i], 1.0f));
        norm_d[base + i] = rsqrtf(fmaxf((float)cnt_d[base + i], 1.0f));
    }
    // scan cnt_d
    int local[32];
    int s = 0;
#pragma unroll
    for (int i = 0; i < 32; ++i) { local[i] = s; s += cnt_d[base + i]; }
    partial[t] = s;
    __syncthreads();
    if (t == 0) {
        int acc = 0;
        for (int i = 0; i < 256; ++i) { offs[i] = acc; acc += partial[i]; }
        offs[256] = acc;
    }
    __syncthreads();
    int o = offs[t];
#pragma unroll
    for (int i = 0; i < 32; ++i) {
        int v = o + local[i];
        row_start[base + i] = v;
        cursor[base + i] = v;
    }
    if (t == 0) row_start[n] = offs[256];
}

__global__ void k_fill(const int* __restrict__ src, const int* __restrict__ dst,
                       int* __restrict__ cursor, int* __restrict__ csr_src, int E) {
    int e = blockIdx.x * blockDim.x + threadIdx.x;
    if (e < E) {
        int pos = atomicAdd(&cursor[dst[e]], 1);
        csr_src[pos] = src[e];
    }
}

// ---------------- linear: Y[row] = (X[row] @ W) * norm[row] ----------------
// 256 threads, 16 rows/block. X-tile staged in LDS (coalesced float4).
// 8 groups of 32 lanes; group g computes rows {2g, 2g+1}, lane covers 4 cols.
template<int K>
__global__ __launch_bounds__(256) void k_linear(const float* __restrict__ X,
                                                const float* __restrict__ W,
                                                const float* __restrict__ norm,
                                                float* __restrict__ Y) {
    __shared__ float xs[16][K];
    int t = threadIdx.x;
    int row0 = blockIdx.x * 16;
    constexpr int K4 = K / 4;
    constexpr int NCH = 16 * K4 / 256;
#pragma unroll
    for (int i = 0; i < NCH; ++i) {
        int c = t + i * 256;
        int r = c / K4, k4 = c % K4;
        *(float4*)&xs[r][k4 * 4] = *(const float4*)(X + (size_t)(row0 + r) * K + k4 * 4);
    }
    __syncthreads();

    int lane = t & 31, g = t >> 5;
    int r0 = g * 2, r1 = g * 2 + 1;
    int c = lane * 4;
    f32x4 acc0 = {0.f, 0.f, 0.f, 0.f}, acc1 = {0.f, 0.f, 0.f, 0.f};
    for (int k = 0; k < K; k += 4) {
        f32x4 x0 = *(f32x4*)&xs[r0][k];
        f32x4 x1 = *(f32x4*)&xs[r1][k];
#pragma unroll
        for (int kk = 0; kk < 4; ++kk) {
            f32x4 w = *(const f32x4*)(W + (size_t)(k + kk) * FDIM + c);
            acc0 += w * x0[kk];
            acc1 += w * x1[kk];
        }
    }
    float n0 = norm[row0 + r0], n1 = norm[row0 + r1];
    *(f32x4*)(Y + (size_t)(row0 + r0) * FDIM + c) = acc0 * n0;
    *(f32x4*)(Y + (size_t)(row0 + r1) * FDIM + c) = acc1 * n1;
}

// ---------------- gather-aggregate + finalize ----------------
static __device__ inline unsigned short f2bf(float f) {
    union { float f; unsigned int u; } a; a.f = f;
    unsigned int u = a.u;
    unsigned int r = u + 0x7FFFu + ((u >> 16) & 1u);
    return (unsigned short)(r >> 16);
}

template<int MODE>  // 0: relu -> f32 out; 1: identity -> bf16 out
__global__ __launch_bounds__(256) void k_gather_agg(const float* __restrict__ Y,
                                                    const int* __restrict__ row_start,
                                                    const int* __restrict__ csr_src,
                                                    const float* __restrict__ nd,
                                                    const float* __restrict__ bias,
                                                    void* __restrict__ outp) {
    int t = threadIdx.x;
    int node = blockIdx.x * 8 + (t >> 5);
    int c4 = (t & 31) << 2;
    int beg = row_start[node], end = row_start[node + 1];
    f32x4 acc = {0.f, 0.f, 0.f, 0.f};
    int e = beg;
    for (; e + 1 < end; e += 2) {
        int s0 = csr_src[e], s1 = csr_src[e + 1];
        f32x4 v0 = *(const f32x4*)(Y + ((size_t)s0 << 7) + c4);
        f32x4 v1 = *(const f32x4*)(Y + ((size_t)s1 << 7) + c4);
        acc += v0;
        acc += v1;
    }
    if (e < end) {
        int s0 = csr_src[e];
        acc += *(const f32x4*)(Y + ((size_t)s0 << 7) + c4);
    }
    float scale = nd[node];
    f32x4 b = *(const f32x4*)(bias + c4);
    f32x4 v = acc * scale + b;
    if (MODE == 0) {
#pragma unroll
        for (int i = 0; i < 4; ++i) v[i] = fmaxf(v[i], 0.f);
        *(f32x4*)((float*)outp + ((size_t)node << 7) + c4) = v;
    } else {
        ushort4 u;
        u.x = f2bf(v[0]); u.y = f2bf(v[1]); u.z = f2bf(v[2]); u.w = f2bf(v[3]);
        *(ushort4*)((unsigned short*)outp + ((size_t)node << 7) + c4) = u;
    }
}

// ---------------- decode: C = sigmoid(H @ H^T), H is [8192][128] bf16 ----------------
__global__ __launch_bounds__(256) void k_decode(const __hip_bfloat16* __restrict__ H,
                                                float* __restrict__ C) {
    __shared__ __align__(16) unsigned char smem[65536];
    unsigned char* sA = smem;
    unsigned char* sB = smem + 32768;
    const int ti = blockIdx.x, tj = blockIdx.y;
    const int t = threadIdx.x;
    const unsigned char* gH = (const unsigned char*)H;

#pragma unroll
    for (int i = 0; i < 8; ++i) {
        int chunk = t + i * 256;
        int row = chunk >> 4;
        int cc = (chunk & 15) << 4;
        int lofs = row * 256 + (cc ^ ((row & 7) << 4));
        *(float4*)(sA + lofs) = *(const float4*)(gH + ((size_t)(ti * 128 + row) << 8) + cc);
        *(float4*)(sB + lofs) = *(const float4*)(gH + ((size_t)(tj * 128 + row) << 8) + cc);
    }
    __syncthreads();

    const int w = t >> 6, lane = t & 63;
    const int wr = (w >> 1) * 64, wc = (w & 1) * 64;
    const int lr = lane & 15;
    const int lk = (lane >> 4) * 16;

    f32x4 acc[4][4] = {};

#pragma unroll
    for (int ks = 0; ks < 4; ++ks) {
        short8 af[4], bfr[4];
#pragma unroll
        for (int mi = 0; mi < 4; ++mi) {
            int row = wr + mi * 16 + lr;
            int off = row * 256 + ((ks * 64 + lk) ^ ((row & 7) << 4));
            af[mi] = *(const short8*)(sA + off);
        }
#pragma unroll
        for (int ni = 0; ni < 4; ++ni) {
            int row = wc + ni * 16 + lr;
            int off = row * 256 + ((ks * 64 + lk) ^ ((row & 7) << 4));
            bfr[ni] = *(const short8*)(sB + off);
        }
#pragma unroll
        for (int mi = 0; mi < 4; ++mi)
#pragma unroll
            for (int ni = 0; ni < 4; ++ni)
                acc[mi][ni] = __builtin_amdgcn_mfma_f32_16x16x32_bf16(af[mi], bfr[ni],
                                                                      acc[mi][ni], 0, 0, 0);
    }

    const int rbase = (lane >> 4) * 4;
    const int cbase = lane & 15;
#pragma unroll
    for (int mi = 0; mi < 4; ++mi) {
#pragma unroll
        for (int ni = 0; ni < 4; ++ni) {
#pragma unroll
            for (int r = 0; r < 4; ++r) {
                int row = ti * 128 + wr + mi * 16 + rbase + r;
                int col = tj * 128 + wc + ni * 16 + cbase;
                float v = acc[mi][ni][r];
                C[(size_t)row * NNODES + col] = 1.0f / (1.0f + __expf(-v));
            }
        }
    }
}

extern "C" void kernel_launch(void* const* d_in, const int* in_sizes, int n_in,
                              void* d_out, int out_size, void* d_ws, size_t ws_size,
                              hipStream_t stream) {
    const float* x  = (const float*)d_in[0];
    const int* src  = (const int*)d_in[1];
    const int* dst  = (const int*)d_in[2];
    const float* W1 = (const float*)d_in[3];
    const float* b1 = (const float*)d_in[4];
    const float* W2 = (const float*)d_in[5];
    const float* b2 = (const float*)d_in[6];
    float* out = (float*)d_out;
    const int E = in_sizes[1];

    char* ws = (char*)d_ws;
    float* norm_s    = (float*)(ws + 0);
    float* norm_d    = (float*)(ws + (32 << 10));
    int*   cnt_s     = (int*)(ws + (64 << 10));    // cnt_s + cnt_d contiguous 64KB
    int*   cnt_d     = (int*)(ws + (96 << 10));
    int*   row_start = (int*)(ws + (128 << 10));   // 8193 ints
    int*   cursor    = (int*)(ws + (164 << 10));
    int*   csr_src   = (int*)(ws + (196 << 10));   // E ints = 1MB
    char*  big       = ws + (196 << 10) + ((size_t)E * 4);
    float* bufA      = (float*)big;                 // 4MB
    float* bufB      = (float*)(big + (4 << 20));   // 4MB
    __hip_bfloat16* h2bf = (__hip_bfloat16*)(big + (8 << 20));  // 2MB

    // zero degree counters (kernel, not memset — graph-friendly, no fill node)
    k_zero<<<(2 * NNODES + 255) / 256, 256, 0, stream>>>(cnt_s, 2 * NNODES);

    // degrees, norms, CSR (graph shared by both layers)
    k_deg_int<<<(E + 255) / 256, 256, 0, stream>>>(src, dst, cnt_s, cnt_d, E);
    k_scan_norms<<<1, 256, 0, stream>>>(cnt_s, cnt_d, norm_s, norm_d, row_start, cursor, NNODES);
    k_fill<<<(E + 255) / 256, 256, 0, stream>>>(src, dst, cursor, csr_src, E);

    // layer 1: y1 = (x@W1)*ns ; h1 = relu(gather(y1)*nd + b1)
    k_linear<256><<<NNODES / 16, 256, 0, stream>>>(x, W1, norm_s, bufA);
    k_gather_agg<0><<<NNODES / 8, 256, 0, stream>>>(bufA, row_start, csr_src, norm_d, b1, bufB);

    // layer 2: y2 = (h1@W2)*ns ; h2 = gather(y2)*nd + b2 -> bf16
    k_linear<128><<<NNODES / 16, 256, 0, stream>>>(bufB, W2, norm_s, bufA);
    k_gather_agg<1><<<NNODES / 8, 256, 0, stream>>>(bufA, row_start, csr_src, norm_d, b2, h2bf);

    // decode: out = sigmoid(h2 @ h2^T)
    k_decode<<<dim3(64, 64), 256, 0, stream>>>(h2bf, out);
}